// Round 1
// baseline (479.574 us; speedup 1.0000x reference)
//
#include <hip/hip_runtime.h>
#include <math.h>

// (B,H,L,D) = (8,8,2048,512).  rows = B*H*L = 131072, FFT length 512.
// Identity:  Re(ifft(W . fft(x))) == ifft(Wp . fft(x)),  Wp[k] = (W[k]+conj(W[(N-k)%N]))/2
// Wp Hermitian => real result for real x; map is C-linear, so two real rows sharing a
// weight row pack as z = x1 + i*x2:  ifft(Wp.fft(z)) = out1 + i*out2 exactly.
// Inverse via forward FFT:  ifft(G) = conj(fft(conj(G)))/N  (the /N is folded into Wp).
//
// This version: 2 packed rows per wave (ILP x2), 128-thread blocks.
//  - twiddles computed once per pair (same role), log-depth power build
//  - weight row loaded/combined once per pair
//  - each lgkmcnt fence covers both rows' LDS traffic

#define HL 16384      // H*L

__device__ __forceinline__ float2 cadd(float2 a, float2 b){ return make_float2(a.x+b.x, a.y+b.y); }
__device__ __forceinline__ float2 csub(float2 a, float2 b){ return make_float2(a.x-b.x, a.y-b.y); }
__device__ __forceinline__ float2 cmul(float2 a, float2 b){ return make_float2(a.x*b.x - a.y*b.y, a.x*b.y + a.y*b.x); }

// exp(-2*pi*i*f), f in revolutions. v_sin_f32/v_cos_f32 take revolutions -> 1 inst each.
__device__ __forceinline__ float2 twiddle(float f) {
    return make_float2(__builtin_amdgcn_cosf(f), -__builtin_amdgcn_sinf(f));
}

// w[k] = exp(-2*pi*i*f*k), k=1..7, log-depth (serial depth 3 vs 6 for the chain build)
__device__ __forceinline__ void twiddle_pows(float f, float2 w[8]) {
    w[1] = twiddle(f);
    w[2] = cmul(w[1], w[1]);
    w[3] = cmul(w[1], w[2]);
    w[4] = cmul(w[2], w[2]);
    w[5] = cmul(w[1], w[4]);
    w[6] = cmul(w[2], w[4]);
    w[7] = cmul(w[3], w[4]);
}

// Wave-level LDS ordering: scratch is private to the wave, so no block barrier needed.
__device__ __forceinline__ void wave_lds_fence() {
    asm volatile("s_waitcnt lgkmcnt(0)" ::: "memory");
    __builtin_amdgcn_wave_barrier();
}

// 8-point DFT, natural order, forward sign.
__device__ __forceinline__ void fft8(float2 x[8]) {
    const float c = 0.70710678118654752f;
    float2 u0 = cadd(x[0], x[4]);
    float2 u1 = cadd(x[1], x[5]);
    float2 u2 = cadd(x[2], x[6]);
    float2 u3 = cadd(x[3], x[7]);
    float2 v0 = csub(x[0], x[4]);
    float2 t1 = csub(x[1], x[5]);
    float2 t2 = csub(x[2], x[6]);
    float2 t3 = csub(x[3], x[7]);
    float2 v1 = make_float2(c*(t1.x + t1.y), c*(t1.y - t1.x));   // * W8^1
    float2 v2 = make_float2(t2.y, -t2.x);                        // * W8^2
    float2 v3 = make_float2(c*(t3.y - t3.x), -c*(t3.x + t3.y));  // * W8^3
    float2 p0 = cadd(u0, u2), p1 = cadd(u1, u3);
    float2 q0 = csub(u0, u2), q1t = csub(u1, u3);
    float2 q1 = make_float2(q1t.y, -q1t.x);
    x[0] = cadd(p0, p1);
    x[4] = csub(p0, p1);
    x[2] = cadd(q0, q1);
    x[6] = csub(q0, q1);
    float2 r0 = cadd(v0, v2), r1 = cadd(v1, v3);
    float2 s0 = csub(v0, v2), s1t = csub(v1, v3);
    float2 s1 = make_float2(s1t.y, -s1t.x);
    x[1] = cadd(r0, r1);
    x[5] = csub(r0, r1);
    x[3] = cadd(s0, s1);
    x[7] = csub(s0, s1);
}

// Dual 512-pt forward FFT, one wave, 8 complex per lane per row, AoS float2 scratch
// (8*72 float2 per row). Both rows use the SAME role -> shared twiddles.
// Input: lane with role r holds z[64*j + r] in v[j].
// Output: lane holds Z[ds(lane) + 64*j] in v[j], ds(r) = ((r&7)<<3)|(r>>3).
// All LDS patterns spread exactly 4 lanes/bank (b64) = bandwidth minimum.
__device__ __forceinline__ void fft512x2(float2 va[8], float2 vb[8],
                                         int role, int lane,
                                         float2* __restrict__ sa,
                                         float2* __restrict__ sb)
{
    // ---- stage 1: radix-8 over stride 64, twiddle W512^{role*k1} ----
    fft8(va);
    fft8(vb);
    {
        float2 w[8];
        twiddle_pows((float)role * (1.0f/512.0f), w);
        #pragma unroll
        for (int k = 1; k < 8; ++k) {
            va[k] = cmul(va[k], w[k]);
            vb[k] = cmul(vb[k], w[k]);
        }
    }
    wave_lds_fence();                // WAR: prior reads of scratch drained
    #pragma unroll
    for (int k1 = 0; k1 < 8; ++k1) {
        sa[k1*72 + role] = va[k1];
        sb[k1*72 + role] = vb[k1];
    }
    wave_lds_fence();
    // ---- stage 2: 8 independent 64-pt FFTs; radix-8 over stride 8 ----
    const int k1 = lane >> 3, m2 = lane & 7;
    float2 ua[8], ub[8];
    #pragma unroll
    for (int m1 = 0; m1 < 8; ++m1) {
        ua[m1] = sa[k1*72 + 8*m1 + m2];
        ub[m1] = sb[k1*72 + 8*m1 + m2];
    }
    fft8(ua);
    fft8(ub);
    {
        float2 w[8];
        twiddle_pows((float)m2 * (1.0f/64.0f), w);
        #pragma unroll
        for (int j = 1; j < 8; ++j) {
            ua[j] = cmul(ua[j], w[j]);
            ub[j] = cmul(ub[j], w[j]);
        }
    }
    wave_lds_fence();                // WAR: stage-2 reads done before overwrite
    #pragma unroll
    for (int j1 = 0; j1 < 8; ++j1) {
        sa[k1*72 + 9*j1 + m2] = ua[j1];
        sb[k1*72 + 9*j1 + m2] = ub[j1];
    }
    wave_lds_fence();
    // ---- stage 3: radix-8 over stride 1, no twiddle ----
    const int j1 = lane & 7;
    #pragma unroll
    for (int m = 0; m < 8; ++m) {
        va[m] = sa[k1*72 + 9*j1 + m];
        vb[m] = sb[k1*72 + 9*j1 + m];
    }
    fft8(va);                        // v[j2] = X[k1 + 8*j1 + 64*j2]
    fft8(vb);
}

__global__ __launch_bounds__(128, 4) void sgn_fft_r8x2(
    const float* __restrict__ x,
    const float* __restrict__ cw,    // (H,L,512,2)
    float* __restrict__ out)
{
    __shared__ float2 sc[2][2][8*72];   // [wave][row][scratch]

    const int tid  = threadIdx.x;
    const int wid  = tid >> 6;       // wave id in [0,2)
    const int lane = tid & 63;
    const int hl   = blockIdx.x;     // weight row, shared by both waves / all rows

    // wave wid handles packed pairs b4 = 2*wid and 2*wid+1 (pair b4 = batches b4, b4+4)
    const int b4a = wid * 2;
    const int b4b = b4a + 1;
    const int r1a = (b4a       * HL + hl) * 512;
    const int r2a = ((b4a + 4) * HL + hl) * 512;
    const int r1b = (b4b       * HL + hl) * 512;
    const int r2b = ((b4b + 4) * HL + hl) * 512;

    const float2* __restrict__ cw2 = (const float2*)cw;
    const int wrow = hl * 512;

    float2* __restrict__ sa = &sc[wid][0][0];
    float2* __restrict__ sb = &sc[wid][1][0];

    // pack: z = x1 + i*x2, lane r holds z[64j + r]; 32 loads issued up front (MLP)
    float2 va[8], vb[8];
    #pragma unroll
    for (int j = 0; j < 8; ++j) {
        va[j].x = x[r1a + 64*j + lane];
        va[j].y = x[r2a + 64*j + lane];
        vb[j].x = x[r1b + 64*j + lane];
        vb[j].y = x[r2b + 64*j + lane];
    }

    fft512x2(va, vb, lane, lane, sa, sb);

    // gate: G = Wp * Z (Wp pre-scaled by 1/512), then conj for inverse-via-forward.
    // Weight row identical for both rows of the pair -> load/combine once.
    const int dsl = ((lane & 7) << 3) | (lane >> 3);
    const float hs = 0.5f / 512.0f;
    #pragma unroll
    for (int j2 = 0; j2 < 8; ++j2) {
        const int k  = dsl + 64*j2;
        const int nk = (512 - k) & 511;
        const float2 wk  = cw2[wrow + k];
        const float2 wnk = cw2[wrow + nk];
        const float2 wp  = make_float2(hs*(wk.x + wnk.x), hs*(wk.y - wnk.y));
        const float2 ga  = cmul(wp, va[j2]);
        const float2 gb  = cmul(wp, vb[j2]);
        va[j2] = make_float2(ga.x, -ga.y);
        vb[j2] = make_float2(gb.x, -gb.y);
    }

    fft512x2(va, vb, dsl, lane, sa, sb);

    // Y = fft(conj(G)); out1 = Re(Y), out2 = -Im(Y) at k = ds(lane)+64*j2
    #pragma unroll
    for (int j2 = 0; j2 < 8; ++j2) {
        const int k = dsl + 64*j2;
        out[r1a + k] =  va[j2].x;
        out[r2a + k] = -va[j2].y;
        out[r1b + k] =  vb[j2].x;
        out[r2b + k] = -vb[j2].y;
    }
}

extern "C" void kernel_launch(void* const* d_in, const int* in_sizes, int n_in,
                              void* d_out, int out_size, void* d_ws, size_t ws_size,
                              hipStream_t stream) {
    const float* x  = (const float*)d_in[0];   // (B,H,L,D) fp32
    // d_in[1] = mask, unused
    const float* cw = (const float*)d_in[2];   // (H,L,D,2) fp32
    float* out = (float*)d_out;

    sgn_fft_r8x2<<<dim3(HL), dim3(128), 0, stream>>>(x, cw, out);
}